// Round 20
// baseline (166.698 us; speedup 1.0000x reference)
//
#include <hip/hip_runtime.h>
#include <cstdint>
#include <cstddef>

#define D_MODEL 1024
#define SEQ     2048
#define NHEADS  16
#define HDIM    64

typedef __attribute__((ext_vector_type(8)))  __bf16 bf16x8;
typedef __attribute__((ext_vector_type(4)))  __bf16 bf16x4;
typedef __attribute__((ext_vector_type(4)))  float  f32x4;
typedef __attribute__((ext_vector_type(16))) float  f32x16;
typedef __attribute__((ext_vector_type(4)))  unsigned u32x4;

// Q pre-scale: 1/sqrt(64) * log2(e)  (QK^T lands directly in log2 domain)
#define QSCALE 0.18033688011112042f

__device__ __forceinline__ void async16(void* lds, const void* g) {
  __builtin_amdgcn_global_load_lds((const __attribute__((address_space(1))) unsigned int*)g,
                                   (__attribute__((address_space(3))) unsigned int*)lds,
                                   16, 0, 0);
}

// XOR swizzle for 128B (64 bf16) rows: flip 16B-slot index by (row&7).
#define SWZ(r, c) ((c) ^ (((r) & 7) << 3))

__device__ __forceinline__ unsigned cvtpk(float lo, float hi) {
  unsigned r;
  asm("v_cvt_pk_bf16_f32 %0, %1, %2" : "=v"(r) : "v"(lo), "v"(hi));
  return r;
}

// raw v_exp_f32 (2^x)
__device__ __forceinline__ float fexp2(float x) {
  float r;
  asm("v_exp_f32 %0, %1" : "=v"(r) : "v"(x));
  return r;
}

__device__ __forceinline__ bf16x8 cvt8(float4 a, float4 b) {
  bf16x8 o;
  o[0]=(__bf16)a.x; o[1]=(__bf16)a.y; o[2]=(__bf16)a.z; o[3]=(__bf16)a.w;
  o[4]=(__bf16)b.x; o[5]=(__bf16)b.y; o[6]=(__bf16)b.z; o[7]=(__bf16)b.w;
  return o;
}

// ---------------- prep_k: conversions + depthwise conv (+x cast), one dispatch
// blocks: [0,3072) cvt3w | [3072,7168) dwconv+cvt_x | [7168,8192) fu2cat
//         [8192,8448) woT | [8448,8704) bconst (wave/row) | [8704,8716) bias3

__global__ __launch_bounds__(256) void prep_k(
    const float* __restrict__ x,
    const float* __restrict__ wq, const float* __restrict__ wk,
    const float* __restrict__ wv,
    const float* __restrict__ bq, const float* __restrict__ bk,
    const float* __restrict__ bv,
    const float* __restrict__ wo, const float* __restrict__ bo,
    const float* __restrict__ fuw, const float* __restrict__ fub,
    const float* __restrict__ dww, const float* __restrict__ dwb,
    __bf16* __restrict__ wqkv, __bf16* __restrict__ xdw,
    __bf16* __restrict__ x_bf,
    __bf16* __restrict__ Wcat, __bf16* __restrict__ woT,
    float* __restrict__ bconst, float* __restrict__ bqkv)
{
  __shared__ float ld[64][65];
  const int bid = blockIdx.x;
  const int t = threadIdx.x;
  if (bid < 3072) {                       // wq|wk|wv -> wqkv bf16
    const float* src = (bid < 1024) ? wq : (bid < 2048) ? wk : wv;
    int i = (bid & 1023) * 1024 + t * 4;
    float4 v = *(const float4*)(src + i);
    bf16x4 o;
    o[0] = (__bf16)v.x; o[1] = (__bf16)v.y; o[2] = (__bf16)v.z; o[3] = (__bf16)v.w;
    *(bf16x4*)(wqkv + (size_t)bid * 1024 + t * 4) = o;
  } else if (bid < 7168) {                // depthwise conv K=3 + x->bf16 cast
    const int bs = bid - 3072;
    int s  = bs & (SEQ - 1);
    int c  = t * 4;
    const float* xr = x + (size_t)bs * D_MODEL + c;
    float4 x0 = *(const float4*)xr;
    float4 xm = {0.f, 0.f, 0.f, 0.f}, xp = {0.f, 0.f, 0.f, 0.f};
    if (s > 0)       xm = *(const float4*)(xr - D_MODEL);
    if (s < SEQ - 1) xp = *(const float4*)(xr + D_MODEL);
    float4 bb = *(const float4*)(dwb + c);
    const float* xmf = (const float*)&xm;
    const float* x0f = (const float*)&x0;
    const float* xpf = (const float*)&xp;
    const float* bbf = (const float*)&bb;
    bf16x4 o, ox;
#pragma unroll
    for (int j = 0; j < 4; ++j) {
      int ch = c + j;
      float a = xmf[j] * dww[ch*3 + 0] + x0f[j] * dww[ch*3 + 1] + xpf[j] * dww[ch*3 + 2] + bbf[j];
      o[j]  = (__bf16)a;
      ox[j] = (__bf16)x0f[j];
    }
    *(bf16x4*)(xdw  + (size_t)bs * D_MODEL + c) = o;
    *(bf16x4*)(x_bf + (size_t)bs * D_MODEL + c) = ox;
  } else if (bid < 8192) {                // fu_w[:,1024:] -> Wcat[:,1024:]
    size_t i = ((size_t)(bid - 7168) * 256 + t) * 4;
    int row = (int)(i >> 10), col = (int)(i & 1023);
    float4 v = *(const float4*)(fuw + (size_t)row * 2048 + 1024 + col);
    bf16x4 o;
    o[0] = (__bf16)v.x; o[1] = (__bf16)v.y; o[2] = (__bf16)v.z; o[3] = (__bf16)v.w;
    *(bf16x4*)&Wcat[(size_t)row * 2048 + 1024 + col] = o;
  } else if (bid < 8448) {                // wo -> woT (64x64 tiles)
    const int idx = bid - 8192;
    const int bi = idx & 15, bj = idx >> 4;
    const int rr = t >> 2, q4 = (t & 3) * 16;
    const float* src = wo + (size_t)(bi * 64 + rr) * 1024 + bj * 64 + q4;
#pragma unroll
    for (int j = 0; j < 4; ++j) {
      float4 v = *(const float4*)(src + j * 4);
      ld[rr][q4 + j*4 + 0] = v.x; ld[rr][q4 + j*4 + 1] = v.y;
      ld[rr][q4 + j*4 + 2] = v.z; ld[rr][q4 + j*4 + 3] = v.w;
    }
    __syncthreads();
    __bf16* dst = woT + (size_t)(bj * 64 + rr) * 1024 + bi * 64 + q4;
#pragma unroll
    for (int j = 0; j < 16; ++j) dst[j] = (__bf16)ld[q4 + j][rr];
  } else if (bid < 8704) {                // bconst: wave per row, coalesced
    const int l = t & 63;
    const int o = (bid - 8448) * 4 + (t >> 6);
    const float* fr = fuw + (size_t)o * 2048;
    float s = 0.f;
#pragma unroll
    for (int pass = 0; pass < 4; ++pass) {
      int c = pass * 256 + l * 4;
      float4 a = *(const float4*)(fr + c);
      float4 b = *(const float4*)(bo + c);
      s += a.x * b.x + a.y * b.y + a.z * b.z + a.w * b.w;
    }
#pragma unroll
    for (int d = 1; d < 64; d <<= 1) s += __shfl_xor(s, d);
    if (l == 0) bconst[o] = fub[o] + s;
  } else {                                // pack_bias3
    int i = (bid - 8704) * 256 + t;
    float v = (i < 1024) ? bq[i] : (i < 2048) ? bk[i - 1024] : bv[i - 2048];
    bqkv[i] = v;
  }
}

// ---------------- GEMM core loop: acc += A[M=128,K] @ W[N=NF*32,K]^T --------
// BK=64 (128B LDS rows, SWZ'd -> conflict-free ds_read_b128), 4 waves.
// AM/WM: 0 = bf16 via global_load_lds (pre-swizzled source col)
//        1 = f32 reg-staged (8 lanes/row, swizzled b128 LDS writes)

template <int AM, int WM, int NF>
__device__ __forceinline__ void gloop64(f32x4 (&acc)[4][NF],
    const void* Ap, int lda, const void* Wp, int ldw, int K,
    __bf16* sA, __bf16* sB, int bm, int bn)
{
  constexpr int BN = NF * 32;
  const int t = threadIdx.x, w = t >> 6, l = t & 63;
  const int wr = (w >> 1) * 64, wc = (w & 1) * (NF * 16);
  const int tl = l & 15, tg = l >> 4;
  const int arow = l >> 3;          // async16: row within 1KB chunk (8 rows)
  const int acs  = (l & 7) * 8;     // dest 16B-slot elem col
  const int frow = t >> 3;          // f32 stage: 8 lanes/row, 32 rows/pass
  const int fcol = (t & 7) * 8;

  for (int k0 = 0; k0 < K; k0 += 64) {
    // ---- A tile (128 rows) ----
    if (AM == 0) {
      const __bf16* Ab = (const __bf16*)Ap + (size_t)(bm * 128) * lda + k0;
#pragma unroll
      for (int p = 0; p < 4; ++p) {
        int c = w * 4 + p, r = c * 8 + arow;
        async16(&sA[c * 512], &Ab[(size_t)r * lda + SWZ(r, acs)]);
      }
    } else {
      const float* Af = (const float*)Ap + (size_t)(bm * 128) * lda + k0;
#pragma unroll
      for (int p = 0; p < 4; ++p) {
        int r = p * 32 + frow;
        const float* s = Af + (size_t)r * lda + fcol;
        float4 v0 = *(const float4*)s, v1 = *(const float4*)(s + 4);
        *(bf16x8*)&sA[r * 64 + SWZ(r, fcol)] = cvt8(v0, v1);
      }
    }
    // ---- W tile (BN rows) ----
    if (WM == 0) {
      const __bf16* Wb = (const __bf16*)Wp + (size_t)(bn * BN) * ldw + k0;
#pragma unroll
      for (int p = 0; p < NF; ++p) {
        int c = w * NF + p, r = c * 8 + arow;
        async16(&sB[c * 512], &Wb[(size_t)r * ldw + SWZ(r, acs)]);
      }
    } else {
      const float* Wf = (const float*)Wp + (size_t)(bn * BN) * ldw + k0;
#pragma unroll
      for (int p = 0; p < NF; ++p) {        // NF passes x 32 rows = BN rows
        int r = p * 32 + frow;
        const float* s = Wf + (size_t)r * ldw + fcol;
        float4 v0 = *(const float4*)s, v1 = *(const float4*)(s + 4);
        *(bf16x8*)&sB[r * 64 + SWZ(r, fcol)] = cvt8(v0, v1);
      }
    }
    __syncthreads();
    bf16x8 af0[4], af1[4], bv0[NF], bv1[NF];
#pragma unroll
    for (int m = 0; m < 4; ++m) {
      int r = wr + m * 16 + tl;
      af0[m] = *(const bf16x8*)&sA[r * 64 + SWZ(r, tg * 8)];
      af1[m] = *(const bf16x8*)&sA[r * 64 + SWZ(r, 32 + tg * 8)];
    }
#pragma unroll
    for (int n = 0; n < NF; ++n) {
      int r = wc + n * 16 + tl;
      bv0[n] = *(const bf16x8*)&sB[r * 64 + SWZ(r, tg * 8)];
      bv1[n] = *(const bf16x8*)&sB[r * 64 + SWZ(r, 32 + tg * 8)];
    }
#pragma unroll
    for (int m = 0; m < 4; ++m)
#pragma unroll
      for (int n = 0; n < NF; ++n) {
        acc[m][n] = __builtin_amdgcn_mfma_f32_16x16x32_bf16(af0[m], bv0[n], acc[m][n], 0, 0, 0);
        acc[m][n] = __builtin_amdgcn_mfma_f32_16x16x32_bf16(af1[m], bv1[n], acc[m][n], 0, 0, 0);
      }
    __syncthreads();
  }
}

// epilogue: EPI 0 = +bias, 1 = +bias & exact GELU, 3 = plain (no bias)
template <int EPI, typename T, int NF>
__device__ __forceinline__ void epi_std(f32x4 (&acc)[4][NF], const float* bias,
                                        T* C, int ldc, int bm, int bn) {
  const int t = threadIdx.x, w = t >> 6, l = t & 63;
  const int wr = (w >> 1) * 64, wc = (w & 1) * (NF * 16);
  const int tl = l & 15, tg = l >> 4;
  const int grow = bm * 128 + wr + tg * 4;
  const int gcolb = bn * (NF * 32) + wc + tl;
#pragma unroll
  for (int n = 0; n < NF; ++n) {
    int col = gcolb + n * 16;
    float bv = (EPI == 3) ? 0.f : bias[col];
#pragma unroll
    for (int m = 0; m < 4; ++m)
#pragma unroll
      for (int r = 0; r < 4; ++r) {
        float v = acc[m][n][r] + bv;
        if (EPI == 1) v = 0.5f * v * (1.0f + erff(v * 0.7071067811865475f));
        C[(size_t)(grow + m * 16 + r) * ldc + col] = (T)v;
      }
  }
}

// ---------------- megawc_k: QKV (768, BN=128) + Wc (128, NF=2) --------------

__global__ __launch_bounds__(256) void megawc_k(
    const __bf16* __restrict__ xb, const __bf16* __restrict__ wqkv,
    const float* __restrict__ bqkv,
    __bf16* __restrict__ qb, __bf16* __restrict__ kb, __bf16* __restrict__ vb,
    const float* __restrict__ fuw, const __bf16* __restrict__ woT,
    __bf16* __restrict__ Wcat)
{
  __shared__ __bf16 sA[128 * 64];
  __shared__ __bf16 sB[128 * 64];
  const int bid = blockIdx.x;                  // 896
  const f32x4 fzero = {0.f, 0.f, 0.f, 0.f};
  if (bid < 768) {                             // QKV: BN=128, 3 blocks/CU
    const int fl = (bid & 7) * 96 + (bid >> 3);
    const int bm = fl / 24, bn = fl % 24;
    f32x4 acc[4][4];
#pragma unroll
    for (int m = 0; m < 4; ++m)
#pragma unroll
      for (int n = 0; n < 4; ++n) acc[m][n] = fzero;
    gloop64<0, 0, 4>(acc, xb, 1024, wqkv, 1024, 1024, sA, sB, bm, bn);

    const int t = threadIdx.x, w = t >> 6, l = t & 63;
    const int wr = (w >> 1) * 64, wc = (w & 1) * 64;
    const int tl = l & 15, tg = l >> 4;
    const int grow = bm * 128 + wr + tg * 4;
    const int gcolb = bn * 128 + wc + tl;
#pragma unroll
    for (int n = 0; n < 4; ++n) {
      int colg = gcolb + n * 16;
      int sel = colg >> 10, cc = colg & 1023;
      __bf16* C = (sel == 0) ? qb : (sel == 1) ? kb : vb;
      float bv = bqkv[colg];
      float scl = (sel == 0) ? QSCALE : 1.0f;
#pragma unroll
      for (int m = 0; m < 4; ++m)
#pragma unroll
        for (int r = 0; r < 4; ++r) {
          float v = (acc[m][n][r] + bv) * scl;
          C[(size_t)(grow + m * 16 + r) * 1024 + cc] = (__bf16)v;
        }
    }
  } else {                                     // Wc = fu_w[:, :1024] @ wo
    const int idx = bid - 768;
    const int fl = (idx & 7) * 16 + (idx >> 3);
    const int bm = fl >> 4, bn = fl & 15;
    f32x4 acc[4][2];
#pragma unroll
    for (int m = 0; m < 4; ++m)
#pragma unroll
      for (int n = 0; n < 2; ++n) acc[m][n] = fzero;
    gloop64<1, 0, 2>(acc, fuw, 2048, woT, 1024, 1024, sA, sB, bm, bn);
    epi_std<3, __bf16, 2>(acc, nullptr, Wcat, 2048, bm, bn);
  }
}

// ---------------- pwvt_k: pointwise+GELU (512) + vtrans (1024) ---------------

__global__ __launch_bounds__(256) void pwvt_k(
    const __bf16* __restrict__ xdw, const float* __restrict__ pww,
    const float* __restrict__ pwb, __bf16* __restrict__ gelu,
    const __bf16* __restrict__ V, __bf16* __restrict__ VT)
{
  __shared__ __align__(16) char smem[24576];
  const int bid = blockIdx.x;                  // 1536
  const int t = threadIdx.x;
  if (bid < 512) {                             // pointwise conv + GELU -> gelu
    __bf16* sA = (__bf16*)smem;                // 16 KB
    __bf16* sB = sA + 8192;                    // 8 KB
    f32x4 acc[4][2];
    const f32x4 fzero = {0.f, 0.f, 0.f, 0.f};
#pragma unroll
    for (int m = 0; m < 4; ++m)
#pragma unroll
      for (int n = 0; n < 2; ++n) acc[m][n] = fzero;
    const int fl = (bid & 7) * 64 + (bid >> 3);
    const int bm = fl >> 4, bn = fl & 15;
    gloop64<0, 1, 2>(acc, xdw, 1024, pww, 1024, 1024, sA, sB, bm, bn);
    epi_std<1, __bf16, 2>(acc, pwb, gelu, 1024, bm, bn);
  } else {                                     // V transpose
    __bf16* ld = (__bf16*)smem;
    const int idx = bid - 512;
    const int stile = idx & 31, h = (idx >> 5) & 15, b = idx >> 9;
    const size_t vbase = ((size_t)(b * SEQ + stile * 64)) * 1024 + h * 64;
#pragma unroll
    for (int p = 0; p < 2; ++p) {
      int r = p * 32 + (t >> 3);
      int c = (t & 7) * 8;
      *(bf16x8*)&ld[r * 64 + (c ^ ((r & 7) << 3))] =
          *(const bf16x8*)&V[vbase + (size_t)r * 1024 + c];
    }
    __syncthreads();
    const size_t obase = ((size_t)(b * NHEADS + h) * 64) * SEQ + stile * 64;
#pragma unroll
    for (int p = 0; p < 2; ++p) {
      int d  = p * 32 + (t >> 3);
      int s8 = (t & 7) * 8;
      bf16x8 vv;
#pragma unroll
      for (int j = 0; j < 8; ++j) {
        int s = s8 + j;
        vv[j] = ld[s * 64 + (((d & 56) ^ ((s & 7) << 3)) + (d & 7))];
      }
      *(bf16x8*)&VT[obase + (size_t)d * SEQ + s8] = vv;
    }
  }
}

// ---------------- fusion: out = attnO@Wc^T + gelu@fu2^T + bconst ------------

__global__ __launch_bounds__(256) void fuse_k(
    const __bf16* __restrict__ attnO, const __bf16* __restrict__ gelu,
    const __bf16* __restrict__ Wcat, const float* __restrict__ bias,
    float* __restrict__ C)
{
  __shared__ __bf16 sA[128 * 64];
  __shared__ __bf16 sB[64 * 64];
  const int flat = blockIdx.x;                 // 512
  const int fl = (flat & 7) * 64 + (flat >> 3);
  const int bm = fl >> 4, bn = fl & 15;
  f32x4 acc[4][2];
  const f32x4 fzero = {0.f, 0.f, 0.f, 0.f};
#pragma unroll
  for (int m = 0; m < 4; ++m)
#pragma unroll
    for (int n = 0; n < 2; ++n) acc[m][n] = fzero;
  gloop64<0, 0, 2>(acc, attnO, 1024, Wcat, 2048, 1024, sA, sB, bm, bn);
  gloop64<0, 0, 2>(acc, gelu, 1024, Wcat + 1024, 2048, 1024, sA, sB, bm, bn);
  epi_std<0, float, 2>(acc, bias, C, 1024, bm, bn);
}

// ---------------- flash attention: KV-split x2, 2-deep pipeline --------------
// Grid 1024: each block does 16 KV tiles of one (qblk,h,b) half. Writes
// UNNORMALIZED bf16 O-partials to O0/O1 and per-(row,head) f32 l to lpart.
// combine_k normalizes in-place. Doubles occupancy (4 blocks/CU, 16 waves).

__device__ __forceinline__ void stage_kv(__bf16* buf,
    const __bf16* __restrict__ Kb, const __bf16* __restrict__ VT,
    size_t kb, size_t vb, int w, int srow, int scol0) {
#pragma unroll
  for (int p = 0; p < 2; ++p) {
    int c = w * 2 + p;
    int r = c * 8 + srow;
    int cg = scol0 ^ ((r & 7) << 3);
    async16(&buf[c * 512], &Kb[kb + (size_t)r * 1024 + cg]);
    async16(&buf[4096 + c * 512], &VT[vb + (size_t)r * SEQ + cg]);
  }
}

__device__ __forceinline__ void qk_step(f32x16& st0, f32x16& st1,
    const __bf16* kbuf, const bf16x8 (&qf)[4], int l31, int hi) {
#pragma unroll
  for (int r = 0; r < 16; ++r) { st0[r] = 0.f; st1[r] = 0.f; }
  __builtin_amdgcn_s_setprio(1);
#pragma unroll
  for (int kk = 0; kk < 4; ++kk) {
    int kc = kk * 16 + 8 * hi;
    bf16x8 kf0 = *(const bf16x8*)&kbuf[l31 * 64 + SWZ(l31, kc)];
    bf16x8 kf1 = *(const bf16x8*)&kbuf[(l31 + 32) * 64 + SWZ(l31 + 32, kc)];
    st0 = __builtin_amdgcn_mfma_f32_32x32x16_bf16(kf0, qf[kk], st0, 0, 0, 0);
    st1 = __builtin_amdgcn_mfma_f32_32x32x16_bf16(kf1, qf[kk], st1, 0, 0, 0);
  }
  __builtin_amdgcn_s_setprio(0);
}

__device__ __forceinline__ void sm_pv(f32x16& st0, f32x16& st1,
    const __bf16* vbuf, f32x16& acc0, f32x16& acc1, f32x16& acc_l,
    const bf16x8& ones, int l31, int hi) {
#pragma unroll
  for (int r = 0; r < 16; ++r) st0[r] = fexp2(st0[r]);
#pragma unroll
  for (int r = 0; r < 16; ++r) st1[r] = fexp2(st1[r]);

  bf16x8 pa[4];
#pragma unroll
  for (int ks = 0; ks < 4; ++ks) {
    const int base = (ks & 1) * 8;
    float p0, p1, p2, p3, p4, p5, p6, p7;
    if (ks < 2) {
      p0 = st0[base+0]; p1 = st0[base+1]; p2 = st0[base+2]; p3 = st0[base+3];
      p4 = st0[base+4]; p5 = st0[base+5]; p6 = st0[base+6]; p7 = st0[base+7];
    } else {
      p0 = st1[base+0]; p1 = st1[base+1]; p2 = st1[base+2]; p3 = st1[base+3];
      p4 = st1[base+4]; p5 = st1[base+5]; p6 = st1[base+6]; p7 = st1[base+7];
    }
    unsigned A1 = cvtpk(p0, p1), A2 = cvtpk(p2, p3);
    unsigned B1 = cvtpk(p4, p5), B2 = cvtpk(p6, p7);
    auto r1 = __builtin_amdgcn_permlane32_swap(A1, B1, false, false);
    auto r2 = __builtin_amdgcn_permlane32_swap(A2, B2, false, false);
    u32x4 pw;
    pw[0] = r1[0]; pw[1] = r2[0]; pw[2] = r1[1]; pw[3] = r2[1];
    pa[ks] = __builtin_bit_cast(bf16x8, pw);
  }

  __builtin_amdgcn_s_setprio(1);
#pragma unroll
  for (int ks = 0; ks < 4; ++ks) {
    int vc = ks * 16 + 8 * hi;
    bf16x8 vf0 = *(const bf16x8*)&vbuf[l31 * 64 + SWZ(l31, vc)];
    bf16x8 vf1 = *(const bf16x8*)&vbuf[(l31 + 32) * 64 + SWZ(l31 + 32, vc)];
    acc0 = __builtin_amdgcn_mfma_f32_32x32x16_bf16(pa[ks], vf0, acc0, 0, 0, 0);
    acc1 = __builtin_amdgcn_mfma_f32_32x32x16_bf16(pa[ks], vf1, acc1, 0, 0, 0);
    acc_l = __builtin_amdgcn_mfma_f32_32x32x16_bf16(pa[ks], ones, acc_l, 0, 0, 0);
  }
  __builtin_amdgcn_s_setprio(0);
}

__global__ __launch_bounds__(256) void attn_k(const __bf16* __restrict__ Q,
                                              const __bf16* __restrict__ Kb,
                                              const __bf16* __restrict__ VT,
                                              __bf16* __restrict__ O0,
                                              __bf16* __restrict__ O1,
                                              float* __restrict__ lpart) {
  const int flat = blockIdx.x;                  // 1024
  const int fl = (flat & 7) * 128 + (flat >> 3);
  const int half = fl & 1, rest = fl >> 1;      // half fastest: shares Q in L2
  const int qblk = rest & 15, h = (rest >> 4) & 15, b = rest >> 8;
  __shared__ __bf16 sKV[3][8192];               // [buf][K 4096 | V 4096]
  __bf16* sQ = sKV[2];                          // overlays buf2 (prologue only)
  const int t = threadIdx.x, w = t >> 6, l = t & 63;
  const int l31 = l & 31, hi = l >> 5;
  const int srow = l >> 3, scol0 = (l & 7) * 8;

  const size_t qbase = ((size_t)(b * SEQ + qblk * 128)) * 1024 + h * 64;
  const size_t kbase = ((size_t)(b * SEQ + half * 1024)) * 1024 + h * 64;
  const size_t vtb   = ((size_t)(b * NHEADS + h) * 64) * SEQ + half * 1024;

  // prologue: stage Q + tiles 0,1 of this half
#pragma unroll
  for (int p = 0; p < 4; ++p) {
    int c = w * 4 + p;
    int r = c * 8 + srow;
    int cg = scol0 ^ ((r & 7) << 3);
    async16(&sQ[c * 512], &Q[qbase + (size_t)r * 1024 + cg]);
  }
  stage_kv(sKV[0], Kb, VT, kbase, vtb, w, srow, scol0);
  stage_kv(sKV[1], Kb, VT, kbase + (size_t)64 * 1024, vtb + 64, w, srow, scol0);
  __syncthreads();

  bf16x8 qf[4];
  const int qr = w * 32 + l31;
#pragma unroll
  for (int kk = 0; kk < 4; ++kk)
    qf[kk] = *(const bf16x8*)&sQ[qr * 64 + SWZ(qr, kk * 16 + 8 * hi)];
  __syncthreads();  // all waves' Q reads done before buf2 restaged

  const __bf16 onev = (__bf16)1.0f;
  const bf16x8 ones = {onev, onev, onev, onev, onev, onev, onev, onev};

  f32x16 acc0, acc1, acc_l;
#pragma unroll
  for (int r = 0; r < 16; ++r) { acc0[r] = 0.f; acc1[r] = 0.f; acc_l[r] = 0.f; }

  f32x16 stA0, stA1, stB0, stB1;
  // QK(0) from buf0
  qk_step(stA0, stA1, sKV[0], qf, l31, hi);

  int kt = 1, bprev = 0, bcur = 1, bnext = 2;

#define ATTN_ITER(C0, C1, P0, P1)                                             \
  do {                                                                        \
    if (kt < 15)                                                              \
      stage_kv(sKV[bnext], Kb, VT, kbase + (size_t)((kt + 1) * 64) * 1024,    \
               vtb + (kt + 1) * 64, w, srow, scol0);                          \
    qk_step(C0, C1, sKV[bcur], qf, l31, hi);                                  \
    sm_pv(P0, P1, sKV[bprev] + 4096, acc0, acc1, acc_l, ones, l31, hi);       \
    __syncthreads();                                                          \
    ++kt;                                                                     \
    int tmp_ = bprev; bprev = bcur; bcur = bnext; bnext = tmp_;               \
  } while (0)

  for (int p7 = 0; p7 < 7; ++p7) {
    ATTN_ITER(stB0, stB1, stA0, stA1);   // kt odd
    ATTN_ITER(stA0, stA1, stB0, stB1);   // kt even
  }
  ATTN_ITER(stB0, stB1, stA0, stA1);     // kt = 15 (no stage)
#undef ATTN_ITER

  // epilogue: softmax+PV for tile 15 (scores in stB, V in buf bprev = 15%3=0)
  sm_pv(stB0, stB1, sKV[bprev] + 4096, acc0, acc1, acc_l, ones, l31, hi);

  // write UNNORMALIZED partials + l
  __bf16* Op = half ? O1 : O0;
  float* lp = lpart + (size_t)half * (4096 * 16);
  const size_t obase = (size_t)(b * SEQ + qblk * 128 + w * 32);
#pragma unroll
  for (int r = 0; r < 16; ++r) {
    int qrow = (r & 3) + 8 * (r >> 2) + 4 * hi;
    size_t row = obase + qrow;
    Op[row * 1024 + h * 64 + l31]      = (__bf16)acc0[r];
    Op[row * 1024 + h * 64 + 32 + l31] = (__bf16)acc1[r];
    if (l31 == 0) lp[row * 16 + h] = acc_l[r];
  }
}

// ---------------- combine: O0 = (O0 + O1) / (l0 + l1), in place --------------

__global__ __launch_bounds__(256) void combine_k(
    __bf16* __restrict__ O0, const __bf16* __restrict__ O1,
    const float* __restrict__ lpart) {
  const int row = blockIdx.x;                  // 4096
  const int c = threadIdx.x * 4;
  const int hh = c >> 6;
  float inv = 1.0f / (lpart[(size_t)row * 16 + hh] +
                      lpart[4096 * 16 + (size_t)row * 16 + hh]);
  bf16x4 a = *(const bf16x4*)&O0[(size_t)row * 1024 + c];
  bf16x4 bb = *(const bf16x4*)&O1[(size_t)row * 1024 + c];
  bf16x4 o;
#pragma unroll
  for (int j = 0; j < 4; ++j)
    o[j] = (__bf16)(((float)a[j] + (float)bb[j]) * inv);
  *(bf16x4*)&O0[(size_t)row * 1024 + c] = o;
}

// ---------------- host ----------------

extern "C" void kernel_launch(void* const* d_in, const int* in_sizes, int n_in,
                              void* d_out, int out_size, void* d_ws, size_t ws_size,
                              hipStream_t stream) {
  (void)in_sizes; (void)n_in; (void)out_size; (void)ws_size;
  const float* x   = (const float*)d_in[0];
  const float* wq  = (const float*)d_in[1];
  const float* bq  = (const float*)d_in[2];
  const float* wk  = (const float*)d_in[3];
  const float* bk  = (const float*)d_in[4];
  const float* wv  = (const float*)d_in[5];
  const float* bv  = (const float*)d_in[6];
  const float* wo  = (const float*)d_in[7];
  const float* bo  = (const float*)d_in[8];
  const float* dww = (const float*)d_in[9];
  const float* dwb = (const float*)d_in[10];
  const float* pww = (const float*)d_in[11];
  const float* pwb = (const float*)d_in[12];
  const float* fuw = (const float*)d_in[13];
  const float* fub = (const float*)d_in[14];
  float* out = (float*)d_out;
  char* ws = (char*)d_ws;

  const size_t MB = 1ull << 20;
  // lifetimes (order: prep -> megawc -> pwvt -> attn -> combine -> fuse):
  // [0,8) qbuf | [8,16) kbuf | [16,24) vbuf -> O0/attnO (after pwvt's vtrans)
  // [24,30) wqkv (dead after megawc) -> [24,32) vt (written by pwvt)
  // [32,40) x_bf (dead after megawc) -> gelu (written by pwvt)
  // [40,44) Wcat | [44,52) xdw (dead after pwvt) -> O1 (written by attn)
  // [52,54) woT (dead after megawc) -> lpart (written by attn)
  // [54,+) bqkv, bconst.  Peak ~54.03 MB (<= proven 55).
  __bf16* qbuf  = (__bf16*)(ws + 0);
  __bf16* kbuf  = (__bf16*)(ws + 8  * MB);
  __bf16* vbuf  = (__bf16*)(ws + 16 * MB);   // dead after pwvt
  __bf16* attnO = (__bf16*)(ws + 16 * MB);   // O0: written by attn, norm in place
  __bf16* wqkv  = (__bf16*)(ws + 24 * MB);   // dead after megawc
  __bf16* vt    = (__bf16*)(ws + 24 * MB);   // written by pwvt
  __bf16* x_bf  = (__bf16*)(ws + 32 * MB);   // dead after megawc
  __bf16* gelu  = (__bf16*)(ws + 32 * MB);   // written by pwvt
  __bf16* Wcat  = (__bf16*)(ws + 40 * MB);
  __bf16* xdw   = (__bf16*)(ws + 44 * MB);   // dead after pwvt
  __bf16* O1    = (__bf16*)(ws + 44 * MB);   // written by attn
  __bf16* woT   = (__bf16*)(ws + 52 * MB);   // dead after megawc
  float*  lpart = (float*) (ws + 52 * MB);   // written by attn (512 KB)
  float*  bqkv  = (float*) (ws + 54 * MB);
  float*  bconst= (float*) (ws + 54 * MB + 16384);

  // conversions + depthwise conv + x cast, one dispatch
  prep_k<<<8716, 256, 0, stream>>>(x, wq, wk, wv, bq, bk, bv, wo, bo,
                                   fuw, fub, dww, dwb,
                                   wqkv, xdw, x_bf, Wcat, woT, bconst, bqkv);

  // QKV projection (BN=128, 3 blocks/CU) + Wc, one dispatch
  megawc_k<<<896, 256, 0, stream>>>(x_bf, wqkv, bqkv, qbuf, kbuf, vbuf,
                                    fuw, woT, Wcat);

  // pointwise conv + GELU + V transpose, one dispatch
  pwvt_k<<<1536, 256, 0, stream>>>(xdw, pww, pwb, gelu, vbuf, vt);

  // attention, KV-split x2 -> unnormalized O0/O1 + lpart
  attn_k<<<1024, 256, 0, stream>>>(qbuf, kbuf, vt, attnO, O1, lpart);

  // combine halves, normalize in place -> attnO
  combine_k<<<4096, 256, 0, stream>>>(attnO, O1, lpart);

  // fusion
  fuse_k<<<512, 256, 0, stream>>>(attnO, gelu, Wcat, bconst, out);
}

// Round 21
// 158.369 us; speedup vs baseline: 1.0526x; 1.0526x over previous
//
#include <hip/hip_runtime.h>
#include <cstdint>
#include <cstddef>

#define D_MODEL 1024
#define SEQ     2048
#define NHEADS  16
#define HDIM    64

typedef __attribute__((ext_vector_type(8)))  __bf16 bf16x8;
typedef __attribute__((ext_vector_type(4)))  __bf16 bf16x4;
typedef __attribute__((ext_vector_type(4)))  float  f32x4;
typedef __attribute__((ext_vector_type(16))) float  f32x16;
typedef __attribute__((ext_vector_type(4)))  unsigned u32x4;

// Q pre-scale: 1/sqrt(64) * log2(e)  (QK^T lands directly in log2 domain)
#define QSCALE 0.18033688011112042f

__device__ __forceinline__ void async16(void* lds, const void* g) {
  __builtin_amdgcn_global_load_lds((const __attribute__((address_space(1))) unsigned int*)g,
                                   (__attribute__((address_space(3))) unsigned int*)lds,
                                   16, 0, 0);
}

// XOR swizzle for 128B (64 bf16) rows: flip 16B-slot index by (row&7).
#define SWZ(r, c) ((c) ^ (((r) & 7) << 3))

__device__ __forceinline__ unsigned cvtpk(float lo, float hi) {
  unsigned r;
  asm("v_cvt_pk_bf16_f32 %0, %1, %2" : "=v"(r) : "v"(lo), "v"(hi));
  return r;
}

// raw v_exp_f32 (2^x)
__device__ __forceinline__ float fexp2(float x) {
  float r;
  asm("v_exp_f32 %0, %1" : "=v"(r) : "v"(x));
  return r;
}

__device__ __forceinline__ bf16x8 cvt8(float4 a, float4 b) {
  bf16x8 o;
  o[0]=(__bf16)a.x; o[1]=(__bf16)a.y; o[2]=(__bf16)a.z; o[3]=(__bf16)a.w;
  o[4]=(__bf16)b.x; o[5]=(__bf16)b.y; o[6]=(__bf16)b.z; o[7]=(__bf16)b.w;
  return o;
}

// ---------------- prep_k: conversions + depthwise conv (+x cast), one dispatch
// blocks: [0,3072) cvt3w | [3072,7168) dwconv+cvt_x | [7168,8192) fu2cat
//         [8192,8448) woT | [8448,8704) bconst (wave/row) | [8704,8716) bias3

__global__ __launch_bounds__(256) void prep_k(
    const float* __restrict__ x,
    const float* __restrict__ wq, const float* __restrict__ wk,
    const float* __restrict__ wv,
    const float* __restrict__ bq, const float* __restrict__ bk,
    const float* __restrict__ bv,
    const float* __restrict__ wo, const float* __restrict__ bo,
    const float* __restrict__ fuw, const float* __restrict__ fub,
    const float* __restrict__ dww, const float* __restrict__ dwb,
    __bf16* __restrict__ wqkv, __bf16* __restrict__ xdw,
    __bf16* __restrict__ x_bf,
    __bf16* __restrict__ Wcat, __bf16* __restrict__ woT,
    float* __restrict__ bconst, float* __restrict__ bqkv)
{
  __shared__ float ld[64][65];
  const int bid = blockIdx.x;
  const int t = threadIdx.x;
  if (bid < 3072) {                       // wq|wk|wv -> wqkv bf16
    const float* src = (bid < 1024) ? wq : (bid < 2048) ? wk : wv;
    int i = (bid & 1023) * 1024 + t * 4;
    float4 v = *(const float4*)(src + i);
    bf16x4 o;
    o[0] = (__bf16)v.x; o[1] = (__bf16)v.y; o[2] = (__bf16)v.z; o[3] = (__bf16)v.w;
    *(bf16x4*)(wqkv + (size_t)bid * 1024 + t * 4) = o;
  } else if (bid < 7168) {                // depthwise conv K=3 + x->bf16 cast
    const int bs = bid - 3072;
    int s  = bs & (SEQ - 1);
    int c  = t * 4;
    const float* xr = x + (size_t)bs * D_MODEL + c;
    float4 x0 = *(const float4*)xr;
    float4 xm = {0.f, 0.f, 0.f, 0.f}, xp = {0.f, 0.f, 0.f, 0.f};
    if (s > 0)       xm = *(const float4*)(xr - D_MODEL);
    if (s < SEQ - 1) xp = *(const float4*)(xr + D_MODEL);
    float4 bb = *(const float4*)(dwb + c);
    const float* xmf = (const float*)&xm;
    const float* x0f = (const float*)&x0;
    const float* xpf = (const float*)&xp;
    const float* bbf = (const float*)&bb;
    bf16x4 o, ox;
#pragma unroll
    for (int j = 0; j < 4; ++j) {
      int ch = c + j;
      float a = xmf[j] * dww[ch*3 + 0] + x0f[j] * dww[ch*3 + 1] + xpf[j] * dww[ch*3 + 2] + bbf[j];
      o[j]  = (__bf16)a;
      ox[j] = (__bf16)x0f[j];
    }
    *(bf16x4*)(xdw  + (size_t)bs * D_MODEL + c) = o;
    *(bf16x4*)(x_bf + (size_t)bs * D_MODEL + c) = ox;
  } else if (bid < 8192) {                // fu_w[:,1024:] -> Wcat[:,1024:]
    size_t i = ((size_t)(bid - 7168) * 256 + t) * 4;
    int row = (int)(i >> 10), col = (int)(i & 1023);
    float4 v = *(const float4*)(fuw + (size_t)row * 2048 + 1024 + col);
    bf16x4 o;
    o[0] = (__bf16)v.x; o[1] = (__bf16)v.y; o[2] = (__bf16)v.z; o[3] = (__bf16)v.w;
    *(bf16x4*)&Wcat[(size_t)row * 2048 + 1024 + col] = o;
  } else if (bid < 8448) {                // wo -> woT (64x64 tiles)
    const int idx = bid - 8192;
    const int bi = idx & 15, bj = idx >> 4;
    const int rr = t >> 2, q4 = (t & 3) * 16;
    const float* src = wo + (size_t)(bi * 64 + rr) * 1024 + bj * 64 + q4;
#pragma unroll
    for (int j = 0; j < 4; ++j) {
      float4 v = *(const float4*)(src + j * 4);
      ld[rr][q4 + j*4 + 0] = v.x; ld[rr][q4 + j*4 + 1] = v.y;
      ld[rr][q4 + j*4 + 2] = v.z; ld[rr][q4 + j*4 + 3] = v.w;
    }
    __syncthreads();
    __bf16* dst = woT + (size_t)(bj * 64 + rr) * 1024 + bi * 64 + q4;
#pragma unroll
    for (int j = 0; j < 16; ++j) dst[j] = (__bf16)ld[q4 + j][rr];
  } else if (bid < 8704) {                // bconst: wave per row, coalesced
    const int l = t & 63;
    const int o = (bid - 8448) * 4 + (t >> 6);
    const float* fr = fuw + (size_t)o * 2048;
    float s = 0.f;
#pragma unroll
    for (int pass = 0; pass < 4; ++pass) {
      int c = pass * 256 + l * 4;
      float4 a = *(const float4*)(fr + c);
      float4 b = *(const float4*)(bo + c);
      s += a.x * b.x + a.y * b.y + a.z * b.z + a.w * b.w;
    }
#pragma unroll
    for (int d = 1; d < 64; d <<= 1) s += __shfl_xor(s, d);
    if (l == 0) bconst[o] = fub[o] + s;
  } else {                                // pack_bias3
    int i = (bid - 8704) * 256 + t;
    float v = (i < 1024) ? bq[i] : (i < 2048) ? bk[i - 1024] : bv[i - 2048];
    bqkv[i] = v;
  }
}

// ---------------- GEMM core loop: acc += A[M=128,K] @ W[N=NF*32,K]^T --------
// BK=64 (128B LDS rows, SWZ'd -> conflict-free ds_read_b128), 4 waves.
// AM/WM: 0 = bf16 via global_load_lds (pre-swizzled source col)
//        1 = f32 reg-staged (8 lanes/row, swizzled b128 LDS writes)

template <int AM, int WM, int NF>
__device__ __forceinline__ void gloop64(f32x4 (&acc)[4][NF],
    const void* Ap, int lda, const void* Wp, int ldw, int K,
    __bf16* sA, __bf16* sB, int bm, int bn)
{
  constexpr int BN = NF * 32;
  const int t = threadIdx.x, w = t >> 6, l = t & 63;
  const int wr = (w >> 1) * 64, wc = (w & 1) * (NF * 16);
  const int tl = l & 15, tg = l >> 4;
  const int arow = l >> 3;          // async16: row within 1KB chunk (8 rows)
  const int acs  = (l & 7) * 8;     // dest 16B-slot elem col
  const int frow = t >> 3;          // f32 stage: 8 lanes/row, 32 rows/pass
  const int fcol = (t & 7) * 8;

  for (int k0 = 0; k0 < K; k0 += 64) {
    // ---- A tile (128 rows) ----
    if (AM == 0) {
      const __bf16* Ab = (const __bf16*)Ap + (size_t)(bm * 128) * lda + k0;
#pragma unroll
      for (int p = 0; p < 4; ++p) {
        int c = w * 4 + p, r = c * 8 + arow;
        async16(&sA[c * 512], &Ab[(size_t)r * lda + SWZ(r, acs)]);
      }
    } else {
      const float* Af = (const float*)Ap + (size_t)(bm * 128) * lda + k0;
#pragma unroll
      for (int p = 0; p < 4; ++p) {
        int r = p * 32 + frow;
        const float* s = Af + (size_t)r * lda + fcol;
        float4 v0 = *(const float4*)s, v1 = *(const float4*)(s + 4);
        *(bf16x8*)&sA[r * 64 + SWZ(r, fcol)] = cvt8(v0, v1);
      }
    }
    // ---- W tile (BN rows) ----
    if (WM == 0) {
      const __bf16* Wb = (const __bf16*)Wp + (size_t)(bn * BN) * ldw + k0;
#pragma unroll
      for (int p = 0; p < NF; ++p) {
        int c = w * NF + p, r = c * 8 + arow;
        async16(&sB[c * 512], &Wb[(size_t)r * ldw + SWZ(r, acs)]);
      }
    } else {
      const float* Wf = (const float*)Wp + (size_t)(bn * BN) * ldw + k0;
#pragma unroll
      for (int p = 0; p < NF; ++p) {        // NF passes x 32 rows = BN rows
        int r = p * 32 + frow;
        const float* s = Wf + (size_t)r * ldw + fcol;
        float4 v0 = *(const float4*)s, v1 = *(const float4*)(s + 4);
        *(bf16x8*)&sB[r * 64 + SWZ(r, fcol)] = cvt8(v0, v1);
      }
    }
    __syncthreads();
    bf16x8 af0[4], af1[4], bv0[NF], bv1[NF];
#pragma unroll
    for (int m = 0; m < 4; ++m) {
      int r = wr + m * 16 + tl;
      af0[m] = *(const bf16x8*)&sA[r * 64 + SWZ(r, tg * 8)];
      af1[m] = *(const bf16x8*)&sA[r * 64 + SWZ(r, 32 + tg * 8)];
    }
#pragma unroll
    for (int n = 0; n < NF; ++n) {
      int r = wc + n * 16 + tl;
      bv0[n] = *(const bf16x8*)&sB[r * 64 + SWZ(r, tg * 8)];
      bv1[n] = *(const bf16x8*)&sB[r * 64 + SWZ(r, 32 + tg * 8)];
    }
#pragma unroll
    for (int m = 0; m < 4; ++m)
#pragma unroll
      for (int n = 0; n < NF; ++n) {
        acc[m][n] = __builtin_amdgcn_mfma_f32_16x16x32_bf16(af0[m], bv0[n], acc[m][n], 0, 0, 0);
        acc[m][n] = __builtin_amdgcn_mfma_f32_16x16x32_bf16(af1[m], bv1[n], acc[m][n], 0, 0, 0);
      }
    __syncthreads();
  }
}

// epilogue: EPI 0 = +bias, 1 = +bias & exact GELU, 3 = plain (no bias)
template <int EPI, typename T, int NF>
__device__ __forceinline__ void epi_std(f32x4 (&acc)[4][NF], const float* bias,
                                        T* C, int ldc, int bm, int bn) {
  const int t = threadIdx.x, w = t >> 6, l = t & 63;
  const int wr = (w >> 1) * 64, wc = (w & 1) * (NF * 16);
  const int tl = l & 15, tg = l >> 4;
  const int grow = bm * 128 + wr + tg * 4;
  const int gcolb = bn * (NF * 32) + wc + tl;
#pragma unroll
  for (int n = 0; n < NF; ++n) {
    int col = gcolb + n * 16;
    float bv = (EPI == 3) ? 0.f : bias[col];
#pragma unroll
    for (int m = 0; m < 4; ++m)
#pragma unroll
      for (int r = 0; r < 4; ++r) {
        float v = acc[m][n][r] + bv;
        if (EPI == 1) v = 0.5f * v * (1.0f + erff(v * 0.7071067811865475f));
        C[(size_t)(grow + m * 16 + r) * ldc + col] = (T)v;
      }
  }
}

// ---------------- megawc_k: QKV (768, BN=128) + Wc (128, NF=2) --------------
// Wc is off the critical path; its 128 blocks fill megaqkv's tail.

__global__ __launch_bounds__(256) void megawc_k(
    const __bf16* __restrict__ xb, const __bf16* __restrict__ wqkv,
    const float* __restrict__ bqkv,
    __bf16* __restrict__ qb, __bf16* __restrict__ kb, __bf16* __restrict__ vb,
    const float* __restrict__ fuw, const __bf16* __restrict__ woT,
    __bf16* __restrict__ Wcat)
{
  __shared__ __bf16 sA[128 * 64];
  __shared__ __bf16 sB[128 * 64];
  const int bid = blockIdx.x;                  // 896
  const f32x4 fzero = {0.f, 0.f, 0.f, 0.f};
  if (bid < 768) {                             // QKV: BN=128, 3 blocks/CU
    const int fl = (bid & 7) * 96 + (bid >> 3);
    const int bm = fl / 24, bn = fl % 24;
    f32x4 acc[4][4];
#pragma unroll
    for (int m = 0; m < 4; ++m)
#pragma unroll
      for (int n = 0; n < 4; ++n) acc[m][n] = fzero;
    gloop64<0, 0, 4>(acc, xb, 1024, wqkv, 1024, 1024, sA, sB, bm, bn);

    const int t = threadIdx.x, w = t >> 6, l = t & 63;
    const int wr = (w >> 1) * 64, wc = (w & 1) * 64;
    const int tl = l & 15, tg = l >> 4;
    const int grow = bm * 128 + wr + tg * 4;
    const int gcolb = bn * 128 + wc + tl;
#pragma unroll
    for (int n = 0; n < 4; ++n) {
      int colg = gcolb + n * 16;
      int sel = colg >> 10, cc = colg & 1023;
      __bf16* C = (sel == 0) ? qb : (sel == 1) ? kb : vb;
      float bv = bqkv[colg];
      float scl = (sel == 0) ? QSCALE : 1.0f;
#pragma unroll
      for (int m = 0; m < 4; ++m)
#pragma unroll
        for (int r = 0; r < 4; ++r) {
          float v = (acc[m][n][r] + bv) * scl;
          C[(size_t)(grow + m * 16 + r) * 1024 + cc] = (__bf16)v;
        }
    }
  } else {                                     // Wc = fu_w[:, :1024] @ wo
    const int idx = bid - 768;
    const int fl = (idx & 7) * 16 + (idx >> 3);
    const int bm = fl >> 4, bn = fl & 15;
    f32x4 acc[4][2];
#pragma unroll
    for (int m = 0; m < 4; ++m)
#pragma unroll
      for (int n = 0; n < 2; ++n) acc[m][n] = fzero;
    gloop64<1, 0, 2>(acc, fuw, 2048, woT, 1024, 1024, sA, sB, bm, bn);
    epi_std<3, __bf16, 2>(acc, nullptr, Wcat, 2048, bm, bn);
  }
}

// ---------------- pwvt_k: pointwise+GELU (512) + vtrans (1024) ---------------

__global__ __launch_bounds__(256) void pwvt_k(
    const __bf16* __restrict__ xdw, const float* __restrict__ pww,
    const float* __restrict__ pwb, __bf16* __restrict__ gelu,
    const __bf16* __restrict__ V, __bf16* __restrict__ VT)
{
  __shared__ __align__(16) char smem[24576];
  const int bid = blockIdx.x;                  // 1536
  const int t = threadIdx.x;
  if (bid < 512) {                             // pointwise conv + GELU -> gelu
    __bf16* sA = (__bf16*)smem;                // 16 KB
    __bf16* sB = sA + 8192;                    // 8 KB
    f32x4 acc[4][2];
    const f32x4 fzero = {0.f, 0.f, 0.f, 0.f};
#pragma unroll
    for (int m = 0; m < 4; ++m)
#pragma unroll
      for (int n = 0; n < 2; ++n) acc[m][n] = fzero;
    const int fl = (bid & 7) * 64 + (bid >> 3);
    const int bm = fl >> 4, bn = fl & 15;
    gloop64<0, 1, 2>(acc, xdw, 1024, pww, 1024, 1024, sA, sB, bm, bn);
    epi_std<1, __bf16, 2>(acc, pwb, gelu, 1024, bm, bn);
  } else {                                     // V transpose
    __bf16* ld = (__bf16*)smem;
    const int idx = bid - 512;
    const int stile = idx & 31, h = (idx >> 5) & 15, b = idx >> 9;
    const size_t vbase = ((size_t)(b * SEQ + stile * 64)) * 1024 + h * 64;
#pragma unroll
    for (int p = 0; p < 2; ++p) {
      int r = p * 32 + (t >> 3);
      int c = (t & 7) * 8;
      *(bf16x8*)&ld[r * 64 + (c ^ ((r & 7) << 3))] =
          *(const bf16x8*)&V[vbase + (size_t)r * 1024 + c];
    }
    __syncthreads();
    const size_t obase = ((size_t)(b * NHEADS + h) * 64) * SEQ + stile * 64;
#pragma unroll
    for (int p = 0; p < 2; ++p) {
      int d  = p * 32 + (t >> 3);
      int s8 = (t & 7) * 8;
      bf16x8 vv;
#pragma unroll
      for (int j = 0; j < 8; ++j) {
        int s = s8 + j;
        vv[j] = ld[s * 64 + (((d & 56) ^ ((s & 7) << 3)) + (d & 7))];
      }
      *(bf16x8*)&VT[obase + (size_t)d * SEQ + s8] = vv;
    }
  }
}

// ---------------- fusion: out = attnO@Wc^T + gelu@fu2^T + bconst ------------

__global__ __launch_bounds__(256) void fuse_k(
    const __bf16* __restrict__ attnO, const __bf16* __restrict__ gelu,
    const __bf16* __restrict__ Wcat, const float* __restrict__ bias,
    float* __restrict__ C)
{
  __shared__ __bf16 sA[128 * 64];
  __shared__ __bf16 sB[64 * 64];
  const int flat = blockIdx.x;                 // 512
  const int fl = (flat & 7) * 64 + (flat >> 3);
  const int bm = fl >> 4, bn = fl & 15;
  f32x4 acc[4][2];
  const f32x4 fzero = {0.f, 0.f, 0.f, 0.f};
#pragma unroll
  for (int m = 0; m < 4; ++m)
#pragma unroll
    for (int n = 0; n < 2; ++n) acc[m][n] = fzero;
  gloop64<0, 0, 2>(acc, attnO, 1024, Wcat, 2048, 1024, sA, sB, bm, bn);
  gloop64<0, 0, 2>(acc, gelu, 1024, Wcat + 1024, 2048, 1024, sA, sB, bm, bn);
  epi_std<0, float, 2>(acc, bias, C, 1024, bm, bn);
}

// ---------------- flash attention: 2-deep software pipeline ------------------
// Triple-buffered K/V (sQ overlays buf2). Race-fixed (R17): __syncthreads()
// after qf loads so no wave restages buf2 while another still reads Q.

__device__ __forceinline__ void stage_kv(__bf16* buf,
    const __bf16* __restrict__ Kb, const __bf16* __restrict__ VT,
    size_t kb, size_t vb, int w, int srow, int scol0) {
#pragma unroll
  for (int p = 0; p < 2; ++p) {
    int c = w * 2 + p;
    int r = c * 8 + srow;
    int cg = scol0 ^ ((r & 7) << 3);
    async16(&buf[c * 512], &Kb[kb + (size_t)r * 1024 + cg]);
    async16(&buf[4096 + c * 512], &VT[vb + (size_t)r * SEQ + cg]);
  }
}

__device__ __forceinline__ void qk_step(f32x16& st0, f32x16& st1,
    const __bf16* kbuf, const bf16x8 (&qf)[4], int l31, int hi) {
#pragma unroll
  for (int r = 0; r < 16; ++r) { st0[r] = 0.f; st1[r] = 0.f; }
  __builtin_amdgcn_s_setprio(1);
#pragma unroll
  for (int kk = 0; kk < 4; ++kk) {
    int kc = kk * 16 + 8 * hi;
    bf16x8 kf0 = *(const bf16x8*)&kbuf[l31 * 64 + SWZ(l31, kc)];
    bf16x8 kf1 = *(const bf16x8*)&kbuf[(l31 + 32) * 64 + SWZ(l31 + 32, kc)];
    st0 = __builtin_amdgcn_mfma_f32_32x32x16_bf16(kf0, qf[kk], st0, 0, 0, 0);
    st1 = __builtin_amdgcn_mfma_f32_32x32x16_bf16(kf1, qf[kk], st1, 0, 0, 0);
  }
  __builtin_amdgcn_s_setprio(0);
}

__device__ __forceinline__ void sm_pv(f32x16& st0, f32x16& st1,
    const __bf16* vbuf, f32x16& acc0, f32x16& acc1, f32x16& acc_l,
    const bf16x8& ones, int l31, int hi) {
#pragma unroll
  for (int r = 0; r < 16; ++r) st0[r] = fexp2(st0[r]);
#pragma unroll
  for (int r = 0; r < 16; ++r) st1[r] = fexp2(st1[r]);

  bf16x8 pa[4];
#pragma unroll
  for (int ks = 0; ks < 4; ++ks) {
    const int base = (ks & 1) * 8;
    float p0, p1, p2, p3, p4, p5, p6, p7;
    if (ks < 2) {
      p0 = st0[base+0]; p1 = st0[base+1]; p2 = st0[base+2]; p3 = st0[base+3];
      p4 = st0[base+4]; p5 = st0[base+5]; p6 = st0[base+6]; p7 = st0[base+7];
    } else {
      p0 = st1[base+0]; p1 = st1[base+1]; p2 = st1[base+2]; p3 = st1[base+3];
      p4 = st1[base+4]; p5 = st1[base+5]; p6 = st1[base+6]; p7 = st1[base+7];
    }
    unsigned A1 = cvtpk(p0, p1), A2 = cvtpk(p2, p3);
    unsigned B1 = cvtpk(p4, p5), B2 = cvtpk(p6, p7);
    auto r1 = __builtin_amdgcn_permlane32_swap(A1, B1, false, false);
    auto r2 = __builtin_amdgcn_permlane32_swap(A2, B2, false, false);
    u32x4 pw;
    pw[0] = r1[0]; pw[1] = r2[0]; pw[2] = r1[1]; pw[3] = r2[1];
    pa[ks] = __builtin_bit_cast(bf16x8, pw);
  }

  __builtin_amdgcn_s_setprio(1);
#pragma unroll
  for (int ks = 0; ks < 4; ++ks) {
    int vc = ks * 16 + 8 * hi;
    bf16x8 vf0 = *(const bf16x8*)&vbuf[l31 * 64 + SWZ(l31, vc)];
    bf16x8 vf1 = *(const bf16x8*)&vbuf[(l31 + 32) * 64 + SWZ(l31 + 32, vc)];
    acc0 = __builtin_amdgcn_mfma_f32_32x32x16_bf16(pa[ks], vf0, acc0, 0, 0, 0);
    acc1 = __builtin_amdgcn_mfma_f32_32x32x16_bf16(pa[ks], vf1, acc1, 0, 0, 0);
    acc_l = __builtin_amdgcn_mfma_f32_32x32x16_bf16(pa[ks], ones, acc_l, 0, 0, 0);
  }
  __builtin_amdgcn_s_setprio(0);
}

__global__ __launch_bounds__(256) void attn_k(const __bf16* __restrict__ Q,
                                              const __bf16* __restrict__ Kb,
                                              const __bf16* __restrict__ VT,
                                              __bf16* __restrict__ Of) {
  const int flat = blockIdx.x;                  // 512
  const int fl = (flat & 7) * 64 + (flat >> 3);
  const int qblk = fl & 15, h = (fl >> 4) & 15, b = fl >> 8;
  __shared__ __bf16 sKV[3][8192];               // [buf][K 4096 | V 4096]
  __bf16* sQ = sKV[2];                          // overlays buf2 (prologue only)
  const int t = threadIdx.x, w = t >> 6, l = t & 63;
  const int l31 = l & 31, hi = l >> 5;
  const int srow = l >> 3, scol0 = (l & 7) * 8;

  const size_t qbase = ((size_t)(b * SEQ + qblk * 128)) * 1024 + h * 64;
  const size_t kbase = ((size_t)(b * SEQ)) * 1024 + h * 64;
  const size_t vtb   = ((size_t)(b * NHEADS + h) * 64) * SEQ;

  // prologue: stage Q + tiles 0,1
#pragma unroll
  for (int p = 0; p < 4; ++p) {
    int c = w * 4 + p;
    int r = c * 8 + srow;
    int cg = scol0 ^ ((r & 7) << 3);
    async16(&sQ[c * 512], &Q[qbase + (size_t)r * 1024 + cg]);
  }
  stage_kv(sKV[0], Kb, VT, kbase, vtb, w, srow, scol0);
  stage_kv(sKV[1], Kb, VT, kbase + (size_t)64 * 1024, vtb + 64, w, srow, scol0);
  __syncthreads();

  bf16x8 qf[4];
  const int qr = w * 32 + l31;
#pragma unroll
  for (int kk = 0; kk < 4; ++kk)
    qf[kk] = *(const bf16x8*)&sQ[qr * 64 + SWZ(qr, kk * 16 + 8 * hi)];
  __syncthreads();  // RACE FIX: all waves' Q reads done before buf2 restaged

  const __bf16 onev = (__bf16)1.0f;
  const bf16x8 ones = {onev, onev, onev, onev, onev, onev, onev, onev};

  f32x16 acc0, acc1, acc_l;
#pragma unroll
  for (int r = 0; r < 16; ++r) { acc0[r] = 0.f; acc1[r] = 0.f; acc_l[r] = 0.f; }

  f32x16 stA0, stA1, stB0, stB1;
  // QK(0) from buf0
  qk_step(stA0, stA1, sKV[0], qf, l31, hi);

  int kt = 1, bprev = 0, bcur = 1, bnext = 2;

#define ATTN_ITER(C0, C1, P0, P1)                                             \
  do {                                                                        \
    if (kt < 31)                                                              \
      stage_kv(sKV[bnext], Kb, VT, kbase + (size_t)((kt + 1) * 64) * 1024,    \
               vtb + (kt + 1) * 64, w, srow, scol0);                          \
    qk_step(C0, C1, sKV[bcur], qf, l31, hi);                                  \
    sm_pv(P0, P1, sKV[bprev] + 4096, acc0, acc1, acc_l, ones, l31, hi);       \
    __syncthreads();                                                          \
    ++kt;                                                                     \
    int tmp_ = bprev; bprev = bcur; bcur = bnext; bnext = tmp_;               \
  } while (0)

  for (int p15 = 0; p15 < 15; ++p15) {
    ATTN_ITER(stB0, stB1, stA0, stA1);   // kt odd
    ATTN_ITER(stA0, stA1, stB0, stB1);   // kt even
  }
  ATTN_ITER(stB0, stB1, stA0, stA1);     // kt = 31 (no stage)
#undef ATTN_ITER

  // epilogue: softmax+PV for tile 31 (scores in stB, V in buf bprev = 31%3)
  sm_pv(stB0, stB1, sKV[bprev] + 4096, acc0, acc1, acc_l, ones, l31, hi);

  const size_t obase = (size_t)(b * SEQ + qblk * 128 + w * 32);
#pragma unroll
  for (int r = 0; r < 16; ++r) {
    int qrow = (r & 3) + 8 * (r >> 2) + 4 * hi;
    float inv = 1.0f / acc_l[r];
    size_t row = (obase + qrow) * 1024 + h * 64;
    Of[row + l31]      = (__bf16)(acc0[r] * inv);
    Of[row + 32 + l31] = (__bf16)(acc1[r] * inv);
  }
}

// ---------------- host ----------------

extern "C" void kernel_launch(void* const* d_in, const int* in_sizes, int n_in,
                              void* d_out, int out_size, void* d_ws, size_t ws_size,
                              hipStream_t stream) {
  (void)in_sizes; (void)n_in; (void)out_size; (void)ws_size;
  const float* x   = (const float*)d_in[0];
  const float* wq  = (const float*)d_in[1];
  const float* bq  = (const float*)d_in[2];
  const float* wk  = (const float*)d_in[3];
  const float* bk  = (const float*)d_in[4];
  const float* wv  = (const float*)d_in[5];
  const float* bv  = (const float*)d_in[6];
  const float* wo  = (const float*)d_in[7];
  const float* bo  = (const float*)d_in[8];
  const float* dww = (const float*)d_in[9];
  const float* dwb = (const float*)d_in[10];
  const float* pww = (const float*)d_in[11];
  const float* pwb = (const float*)d_in[12];
  const float* fuw = (const float*)d_in[13];
  const float* fub = (const float*)d_in[14];
  float* out = (float*)d_out;
  char* ws = (char*)d_ws;

  const size_t MB = 1ull << 20;
  // lifetimes (order: prep -> megawc -> pwvt -> attn -> fuse):
  // [0,8) qbuf | [8,16) kbuf | [16,24) vbuf -> attnO (after pwvt's vtrans)
  // [24,30) wqkv (dead after megawc) -> [24,32) vt (written by pwvt)
  // [32,40) x_bf (dead after megawc) -> gelu (written by pwvt)
  // [40,44) Wcat | [44,52) xdw | [52,54) woT | [54,+) bqkv, bconst.
  // Peak ~54.03 MB (<= proven 55).
  __bf16* qbuf  = (__bf16*)(ws + 0);
  __bf16* kbuf  = (__bf16*)(ws + 8  * MB);
  __bf16* vbuf  = (__bf16*)(ws + 16 * MB);   // dead after pwvt
  __bf16* attnO = (__bf16*)(ws + 16 * MB);   // written by attn
  __bf16* wqkv  = (__bf16*)(ws + 24 * MB);   // dead after megawc
  __bf16* vt    = (__bf16*)(ws + 24 * MB);   // written by pwvt
  __bf16* x_bf  = (__bf16*)(ws + 32 * MB);   // dead after megawc
  __bf16* gelu  = (__bf16*)(ws + 32 * MB);   // written by pwvt
  __bf16* Wcat  = (__bf16*)(ws + 40 * MB);
  __bf16* xdw   = (__bf16*)(ws + 44 * MB);
  __bf16* woT   = (__bf16*)(ws + 52 * MB);
  float*  bqkv  = (float*) (ws + 54 * MB);
  float*  bconst= (float*) (ws + 54 * MB + 16384);

  // conversions + depthwise conv + x cast, one dispatch
  prep_k<<<8716, 256, 0, stream>>>(x, wq, wk, wv, bq, bk, bv, wo, bo,
                                   fuw, fub, dww, dwb,
                                   wqkv, xdw, x_bf, Wcat, woT, bconst, bqkv);

  // QKV projection (BN=128, 3 blocks/CU) + Wc, one dispatch
  megawc_k<<<896, 256, 0, stream>>>(x_bf, wqkv, bqkv, qbuf, kbuf, vbuf,
                                    fuw, woT, Wcat);

  // pointwise conv + GELU + V transpose, one dispatch
  pwvt_k<<<1536, 256, 0, stream>>>(xdw, pww, pwb, gelu, vbuf, vt);

  // attention -> attnO
  attn_k<<<512, 256, 0, stream>>>(qbuf, kbuf, vt, attnO);

  // fusion
  fuse_k<<<512, 256, 0, stream>>>(attnO, gelu, Wcat, bconst, out);
}